// Round 1
// baseline (14599.071 us; speedup 1.0000x reference)
//
#include <hip/hip_runtime.h>

typedef unsigned short u16;
typedef unsigned int u32;
typedef __attribute__((ext_vector_type(8))) __bf16 bf8;
typedef __attribute__((ext_vector_type(4))) float f4;

__device__ __forceinline__ u16 f2bu(float f) {
  u32 u = __float_as_uint(f);
  u = (u + 0x7fffu + ((u >> 16) & 1u)) >> 16;
  return (u16)u;
}
__device__ __forceinline__ float b2f(u16 v) {
  return __uint_as_float(((u32)v) << 16);
}

// ---------------- conversions ----------------
__global__ __launch_bounds__(256) void k_f2b(const float* __restrict__ src,
                                             u16* __restrict__ dst, long n) {
  long i = ((long)blockIdx.x * 256 + threadIdx.x) * 8;
  if (i + 8 > n) return;
  float4 a = *(const float4*)(src + i);
  float4 b = *(const float4*)(src + i + 4);
  union { u16 h[8]; uint4 v; } r;
  r.h[0] = f2bu(a.x); r.h[1] = f2bu(a.y); r.h[2] = f2bu(a.z); r.h[3] = f2bu(a.w);
  r.h[4] = f2bu(b.x); r.h[5] = f2bu(b.y); r.h[6] = f2bu(b.z); r.h[7] = f2bu(b.w);
  *(uint4*)(dst + i) = r.v;
}

__global__ __launch_bounds__(256) void k_bsum(const float* __restrict__ a,
                                              const float* __restrict__ b,
                                              float* __restrict__ o, int n) {
  int i = blockIdx.x * 256 + threadIdx.x;
  if (i < n) o[i] = a[i] + b[i];
}

__global__ __launch_bounds__(64) void k_zerobar(u32* __restrict__ p) {
  if (threadIdx.x < 8) p[threadIdx.x] = 0;
}

// ---------------- big feed-forward GEMMs ----------------
// C[M,N] = A[M,K] @ B[N,K]^T  (bf16 in, fp32 acc), epilogue per MODE.
// MODE 0: out = bf16(relu(acc + bias[n])) at [m*N + n]           (x)
// MODE 1: out = bf16(acc + bias[n]) at [((m&511)*64 + (m>>9))*N + n]  (gx in [T,B,4H])
template<int MODE>
__global__ __launch_bounds__(256) void k_gemm(const u16* __restrict__ A, const u16* __restrict__ B,
                                              const float* __restrict__ bias, u16* __restrict__ out,
                                              int M, int N, int K)
{
  __shared__ u16 As[128][40];   // +8 pad: 2-way banks (free per m136)
  __shared__ u16 Bs[128][40];
  const int tid = threadIdx.x;
  const int bm = blockIdx.y, bn = blockIdx.x;
  const int wave = tid >> 6, lane = tid & 63;
  const int wm = wave & 1, wn = wave >> 1;
  const f4 fzero = {0.f, 0.f, 0.f, 0.f};
  f4 acc[4][4];
#pragma unroll
  for (int i = 0; i < 4; i++)
#pragma unroll
    for (int j = 0; j < 4; j++) acc[i][j] = fzero;

  const u16* Ab = A + (size_t)bm * 128 * K;
  const u16* Bb = B + (size_t)bn * 128 * K;
  const int row_s = tid >> 2;        // 0..63
  const int cs = (tid & 3) * 8;      // col start (elems)

  for (int k0 = 0; k0 < K; k0 += 32) {
    __syncthreads();
#pragma unroll
    for (int L = 0; L < 2; L++) {
      int row = L * 64 + row_s;
      *(uint4*)&As[row][cs] = *(const uint4*)(Ab + (size_t)row * K + k0 + cs);
      *(uint4*)&Bs[row][cs] = *(const uint4*)(Bb + (size_t)row * K + k0 + cs);
    }
    __syncthreads();
    const int kf = (lane >> 4) * 8;
    const int rr = lane & 15;
    bf8 af[4], bfr[4];
#pragma unroll
    for (int i = 0; i < 4; i++) {
      af[i]  = *(const bf8*)&As[wm * 64 + i * 16 + rr][kf];
      bfr[i] = *(const bf8*)&Bs[wn * 64 + i * 16 + rr][kf];
    }
#pragma unroll
    for (int i = 0; i < 4; i++)
#pragma unroll
      for (int j = 0; j < 4; j++)
        acc[i][j] = __builtin_amdgcn_mfma_f32_16x16x32_bf16(af[i], bfr[j], acc[i][j], 0, 0, 0);
  }
  // C/D: n = lane&15, m = (lane>>4)*4 + reg   [measured m89/m91]
  const int mq = (lane >> 4) * 4;
  const int nn = lane & 15;
#pragma unroll
  for (int i = 0; i < 4; i++) {
#pragma unroll
    for (int j = 0; j < 4; j++) {
      int n = bn * 128 + wn * 64 + j * 16 + nn;
      float bv = bias[n];
#pragma unroll
      for (int r = 0; r < 4; r++) {
        int m = bm * 128 + wm * 64 + i * 16 + mq + r;
        float v = acc[i][j][r] + bv;
        if (MODE == 0) {
          v = fmaxf(v, 0.f);
          out[(size_t)m * N + n] = f2bu(v);
        } else {
          out[((size_t)(m & 511) * 64 + (m >> 9)) * (size_t)N + n] = f2bu(v);
        }
      }
    }
  }
}

// ---------------- persistent LSTM scan ----------------
// 256 WGs = 4 batch-quarters x 64 h-slices(16). Each WG owns W_hh rows
// {g*1024 + hs*16 + r : g in 0..3, r in 0..15} resident in LDS (128 KB).
// Per step: gates[16b x 16h x 4g] = h_prev[16,1024] @ Wl^T (MFMA per wave),
// + gx, nonlin, c state in LDS, h -> h_hist[t] (bf16 broadcast buffer).
//
// KEY CHANGE vs previous round: the recurrence couples h-components only
// WITHIN a batch element; the 4 batch-quarter groups (64 WGs each) never
// exchange data (each WG reads hh rows of its own bq only). So the 512
// grid-wide cg::grid_group::sync()s (~45us each, the dominant cost) are
// replaced with a per-bq 64-WG monotonic barrier (generation counter, no
// reset race):  arrive = atomicAdd(cnt[bq]); last arriver of step t sets
// rel[bq]=t+1; others spin on relaxed agent loads. __threadfence() on
// release + acquire sides preserves grid.sync's cross-XCD wbl2/inv
// semantics. Cooperative launch is kept ONLY for the co-residency
// guarantee the spin barrier requires.
__global__ __launch_bounds__(256) void k_scan(const u16* __restrict__ gx,
                                              const u16* __restrict__ Whh,
                                              u16* __restrict__ hh,
                                              u32* __restrict__ bar)
{
  extern __shared__ char smem[];
  u16*  Wl = (u16*)smem;                    // [64][1032]  132096 B
  u16*  hb = (u16*)(smem + 132096);         // [16][520]    16640 B
  float* gl = (float*)(smem + 148736);      // [4][16][16]   4096 B
  float* cl = (float*)(smem + 152832);      // [16][16]      1024 B
  const int tid = threadIdx.x, lane = tid & 63, wv = tid >> 6;
  const int hs = blockIdx.x & 63, bq = blockIdx.x >> 6;
  u32* cnt = bar;        // [4] cumulative arrivals per bq
  u32* rel = bar + 4;    // [4] released generation per bq

  // 64 rows x 128 16B-segs (1024 bf16/row).
  for (int idx = tid; idx < 64 * 128; idx += 256) {
    int r = idx >> 7, s = idx & 127;
    int gr = (r >> 4) * 1024 + hs * 16 + (r & 15);
    *(uint4*)&Wl[r * 1032 + s * 8] = *(const uint4*)(Whh + (size_t)gr * 1024 + s * 8);
  }
  cl[tid] = 0.f;
  __syncthreads();

  const int kf = (lane >> 4) * 8;
  const int ra = lane & 15;
  const int rb = wv * 16 + (lane & 15);
  const int srow = tid >> 4;
  const int sseg = tid & 15;

  for (int t = 0; t < 512; t++) {
    f4 acc = {0.f, 0.f, 0.f, 0.f};
    if (t > 0) {
      const u16* hp = hh + ((size_t)(t - 1) * 64 + bq * 16) * 1024;
      for (int kc = 0; kc < 1024; kc += 512) {
        __syncthreads();
#pragma unroll
        for (int u = 0; u < 4; u++) {
          int s = sseg + u * 16;
          *(uint4*)&hb[srow * 520 + s * 8] = *(const uint4*)(hp + (size_t)srow * 1024 + kc + s * 8);
        }
        __syncthreads();
#pragma unroll
        for (int k = 0; k < 512; k += 32) {
          bf8 a = *(const bf8*)&hb[ra * 520 + k + kf];
          bf8 b = *(const bf8*)&Wl[rb * 1032 + kc + k + kf];
          acc = __builtin_amdgcn_mfma_f32_16x16x32_bf16(a, b, acc, 0, 0, 0);
        }
      }
    }
    {
      int n = lane & 15, m0 = (lane >> 4) * 4;
#pragma unroll
      for (int r = 0; r < 4; r++) gl[wv * 256 + (m0 + r) * 16 + n] = acc[r];
    }
    __syncthreads();
    {
      int b = tid >> 4, hl2 = tid & 15;
      int bg = bq * 16 + b, hg = hs * 16 + hl2;
      size_t gxb = ((size_t)t * 64 + bg) * 4096;
      float gi = gl[0 * 256 + b * 16 + hl2] + b2f(gx[gxb + 0 * 1024 + hg]);
      float gf = gl[1 * 256 + b * 16 + hl2] + b2f(gx[gxb + 1 * 1024 + hg]);
      float gg = gl[2 * 256 + b * 16 + hl2] + b2f(gx[gxb + 2 * 1024 + hg]);
      float go = gl[3 * 256 + b * 16 + hl2] + b2f(gx[gxb + 3 * 1024 + hg]);
      float i_ = 1.f / (1.f + __expf(-gi));
      float f_ = 1.f / (1.f + __expf(-gf));
      float g_ = 1.f - 2.f / (__expf(2.f * gg) + 1.f);   // tanh
      float o_ = 1.f / (1.f + __expf(-go));
      float c = f_ * cl[tid] + i_ * g_;
      cl[tid] = c;
      float h = o_ * (1.f - 2.f / (__expf(2.f * c) + 1.f));
      hh[((size_t)t * 64 + bg) * 1024 + hg] = f2bu(h);
    }
    // ---- per-bq barrier (replaces grid.sync) ----
    __syncthreads();               // all h-writes of this WG issued
    if (tid == 0) {
      __threadfence();             // agent release: drain + L2 writeback
      u32 old = __hip_atomic_fetch_add(&cnt[bq], 1u, __ATOMIC_RELAXED,
                                       __HIP_MEMORY_SCOPE_AGENT);
      if (old == 64u * (u32)(t + 1) - 1u) {
        __hip_atomic_store(&rel[bq], (u32)(t + 1), __ATOMIC_RELAXED,
                           __HIP_MEMORY_SCOPE_AGENT);
      } else {
        while (__hip_atomic_load(&rel[bq], __ATOMIC_RELAXED,
                                 __HIP_MEMORY_SCOPE_AGENT) < (u32)(t + 1))
          __builtin_amdgcn_s_sleep(2);
      }
      __threadfence();             // agent acquire: L1/L2 invalidate
    }
    __syncthreads();
  }
}

// ---------------- classifier over all (t,b) ----------------
__global__ __launch_bounds__(256) void k_scores(const u16* __restrict__ hh,
                                                const u16* __restrict__ Wcb,
                                                const float* __restrict__ bcls,
                                                float* __restrict__ out)
{
  __shared__ u16 Wc[22 * 1032];   // padded rows
  __shared__ u16 hl[8 * 1032];
  const int tid = threadIdx.x;
  for (int idx = tid; idx < 22 * 128; idx += 256) {
    int r = idx >> 7, s = idx & 127;
    *(uint4*)&Wc[r * 1032 + s * 8] = *(const uint4*)(Wcb + (size_t)r * 1024 + s * 8);
  }
  size_t row0 = (size_t)blockIdx.x * 8;
  for (int idx = tid; idx < 8 * 128; idx += 256) {
    int r = idx >> 7, s = idx & 127;
    *(uint4*)&hl[r * 1032 + s * 8] = *(const uint4*)(hh + (row0 + r) * 1024 + s * 8);
  }
  __syncthreads();
  if (tid < 176) {
    int rl = tid / 22, cls = tid % 22;
    const u16* hp = &hl[rl * 1032];
    const u16* wp = &Wc[cls * 1032];
    float acc = 0.f;
#pragma unroll 4
    for (int k = 0; k < 1024; k += 2) {
      u32 hu = *(const u32*)(hp + k);
      u32 wu = *(const u32*)(wp + k);
      float h0 = __uint_as_float(hu << 16), h1 = __uint_as_float(hu & 0xffff0000u);
      float w0 = __uint_as_float(wu << 16), w1 = __uint_as_float(wu & 0xffff0000u);
      acc += h0 * w0 + h1 * w1;
    }
    size_t r = row0 + rl;
    int t = (int)(r >> 6), b = (int)(r & 63);
    out[((size_t)b * 512 + t) * 22 + cls] = acc + bcls[cls];
  }
}

// ---------------- host ----------------
extern "C" void kernel_launch(void* const* d_in, const int* in_sizes, int n_in,
                              void* d_out, int out_size, void* d_ws, size_t ws_size,
                              hipStream_t stream)
{
  (void)in_sizes; (void)n_in; (void)out_size;
  const float* feat = (const float*)d_in[0];
  const float* Wpre = (const float*)d_in[1];
  const float* bpre = (const float*)d_in[2];
  const float* Wih  = (const float*)d_in[3];
  const float* bih  = (const float*)d_in[4];
  const float* Whh  = (const float*)d_in[5];
  const float* bhh  = (const float*)d_in[6];
  const float* Wcls = (const float*)d_in[7];
  const float* bcls = (const float*)d_in[8];
  char* ws = (char*)d_ws;

  // workspace layout:
  //   featb (201 MB) overlays gx region (dead before gemm<1> writes gx)
  //   hh (64 MB) overlays xb (x dead after gemm<1>)
  const size_t OFF_GX   = 0;          // gx bf16 [512][64][4096] = 256 MB
  const size_t OFF_XB   = 268435456;  // x bf16 [32768][1024] = 64 MB; hh overlay
  const size_t OFF_WPRE = 335544320;  // 6 MB
  const size_t OFF_WIH  = 341835776;  // 8 MB
  const size_t OFF_WHH  = 350224384;  // 8 MB
  const size_t OFF_WCLS = 358612992;  // 44 KB
  const size_t OFF_BSUM = 358658048;  // 16 KB
  const size_t OFF_BAR  = 358674432;  // 4 KB barrier state (cnt[4], rel[4])
  const size_t NEED     = 358678528;
  if (ws_size < NEED) return;  // graceful fail (absmax) instead of OOB fault

  u16* featb = (u16*)(ws + OFF_GX);
  u16* gxb   = (u16*)(ws + OFF_GX);
  u16* xb    = (u16*)(ws + OFF_XB);
  u16* hhb   = (u16*)(ws + OFF_XB);   // overlay, x dead by scan time
  u16* wpreb = (u16*)(ws + OFF_WPRE);
  u16* wihb  = (u16*)(ws + OFF_WIH);
  u16* whhb  = (u16*)(ws + OFF_WHH);
  u16* wclsb = (u16*)(ws + OFF_WCLS);
  float* bsum = (float*)(ws + OFF_BSUM);
  u32* barp  = (u32*)(ws + OFF_BAR);

  // feature_in: 64*512*3072 = 100,663,296 elems
  k_f2b<<<dim3(49152), dim3(256), 0, stream>>>(feat, featb, 100663296L);
  k_f2b<<<dim3(1536),  dim3(256), 0, stream>>>(Wpre, wpreb, 3145728L);
  k_f2b<<<dim3(2048),  dim3(256), 0, stream>>>(Wih,  wihb,  4194304L);
  k_f2b<<<dim3(2048),  dim3(256), 0, stream>>>(Whh,  whhb,  4194304L);
  k_f2b<<<dim3(11),    dim3(256), 0, stream>>>(Wcls, wclsb, 22528L);
  k_bsum<<<dim3(16),   dim3(256), 0, stream>>>(bih, bhh, bsum, 4096);
  k_zerobar<<<dim3(1), dim3(64),  0, stream>>>(barp);

  k_gemm<0><<<dim3(8, 256),  dim3(256), 0, stream>>>(featb, wpreb, bpre, xb,  32768, 1024, 3072);
  k_gemm<1><<<dim3(32, 256), dim3(256), 0, stream>>>(xb,    wihb,  bsum, gxb, 32768, 4096, 1024);

  const u16* gx_c = gxb;
  const u16* whh_c = whhb;
  u16* hh_p = hhb;
  u32* bar_p = barp;
  void* args[4] = { (void*)&gx_c, (void*)&whh_c, (void*)&hh_p, (void*)&bar_p };
  hipFuncSetAttribute((const void*)k_scan, hipFuncAttributeMaxDynamicSharedMemorySize, 153856);
  hipLaunchCooperativeKernel((void*)k_scan, dim3(256), dim3(256), args, 153856, stream);

  k_scores<<<dim3(4096), dim3(256), 0, stream>>>(hhb, wclsb, bcls, (float*)d_out);
}

// Round 2
// 8022.009 us; speedup vs baseline: 1.8199x; 1.8199x over previous
//
#include <hip/hip_runtime.h>

typedef unsigned short u16;
typedef unsigned int u32;
typedef __attribute__((ext_vector_type(8))) __bf16 bf8;
typedef __attribute__((ext_vector_type(4))) float f4;

__device__ __forceinline__ u16 f2bu(float f) {
  u32 u = __float_as_uint(f);
  u = (u + 0x7fffu + ((u >> 16) & 1u)) >> 16;
  return (u16)u;
}
__device__ __forceinline__ float b2f(u16 v) {
  return __uint_as_float(((u32)v) << 16);
}

// ---------------- conversions ----------------
__global__ __launch_bounds__(256) void k_f2b(const float* __restrict__ src,
                                             u16* __restrict__ dst, long n) {
  long i = ((long)blockIdx.x * 256 + threadIdx.x) * 8;
  if (i + 8 > n) return;
  float4 a = *(const float4*)(src + i);
  float4 b = *(const float4*)(src + i + 4);
  union { u16 h[8]; uint4 v; } r;
  r.h[0] = f2bu(a.x); r.h[1] = f2bu(a.y); r.h[2] = f2bu(a.z); r.h[3] = f2bu(a.w);
  r.h[4] = f2bu(b.x); r.h[5] = f2bu(b.y); r.h[6] = f2bu(b.z); r.h[7] = f2bu(b.w);
  *(uint4*)(dst + i) = r.v;
}

__global__ __launch_bounds__(256) void k_bsum(const float* __restrict__ a,
                                              const float* __restrict__ b,
                                              float* __restrict__ o, int n) {
  int i = blockIdx.x * 256 + threadIdx.x;
  if (i < n) o[i] = a[i] + b[i];
}

// clears rel (4 x 64 u32 lines) + flags (4*64 x 16 u32 lines) = 4352 u32
__global__ __launch_bounds__(256) void k_zerobar(u32* __restrict__ p) {
  for (int i = threadIdx.x; i < 4352; i += 256) p[i] = 0;
}

// ---------------- big feed-forward GEMMs ----------------
// C[M,N] = A[M,K] @ B[N,K]^T  (bf16 in, fp32 acc), epilogue per MODE.
// MODE 0: out = bf16(relu(acc + bias[n])) at [m*N + n]                (x)
// MODE 1: out = bf16(acc + bias[n]) scattered into gx layout
//         [t][bq][hs][g][16b][16h]  (t=m&511, b=m>>9, g=n>>10, hg=n&1023)
//         so each scan WG's per-step gx read is 4 x 512B contiguous.
template<int MODE>
__global__ __launch_bounds__(256) void k_gemm(const u16* __restrict__ A, const u16* __restrict__ B,
                                              const float* __restrict__ bias, u16* __restrict__ out,
                                              int M, int N, int K)
{
  __shared__ u16 As[128][40];   // +8 pad: 2-way banks (free per m136)
  __shared__ u16 Bs[128][40];
  const int tid = threadIdx.x;
  const int bm = blockIdx.y, bn = blockIdx.x;
  const int wave = tid >> 6, lane = tid & 63;
  const int wm = wave & 1, wn = wave >> 1;
  const f4 fzero = {0.f, 0.f, 0.f, 0.f};
  f4 acc[4][4];
#pragma unroll
  for (int i = 0; i < 4; i++)
#pragma unroll
    for (int j = 0; j < 4; j++) acc[i][j] = fzero;

  const u16* Ab = A + (size_t)bm * 128 * K;
  const u16* Bb = B + (size_t)bn * 128 * K;
  const int row_s = tid >> 2;        // 0..63
  const int cs = (tid & 3) * 8;      // col start (elems)

  for (int k0 = 0; k0 < K; k0 += 32) {
    __syncthreads();
#pragma unroll
    for (int L = 0; L < 2; L++) {
      int row = L * 64 + row_s;
      *(uint4*)&As[row][cs] = *(const uint4*)(Ab + (size_t)row * K + k0 + cs);
      *(uint4*)&Bs[row][cs] = *(const uint4*)(Bb + (size_t)row * K + k0 + cs);
    }
    __syncthreads();
    const int kf = (lane >> 4) * 8;
    const int rr = lane & 15;
    bf8 af[4], bfr[4];
#pragma unroll
    for (int i = 0; i < 4; i++) {
      af[i]  = *(const bf8*)&As[wm * 64 + i * 16 + rr][kf];
      bfr[i] = *(const bf8*)&Bs[wn * 64 + i * 16 + rr][kf];
    }
#pragma unroll
    for (int i = 0; i < 4; i++)
#pragma unroll
      for (int j = 0; j < 4; j++)
        acc[i][j] = __builtin_amdgcn_mfma_f32_16x16x32_bf16(af[i], bfr[j], acc[i][j], 0, 0, 0);
  }
  // C/D: n = lane&15, m = (lane>>4)*4 + reg   [measured m89/m91]
  const int mq = (lane >> 4) * 4;
  const int nn = lane & 15;
#pragma unroll
  for (int i = 0; i < 4; i++) {
#pragma unroll
    for (int j = 0; j < 4; j++) {
      int n = bn * 128 + wn * 64 + j * 16 + nn;
      float bv = bias[n];
#pragma unroll
      for (int r = 0; r < 4; r++) {
        int m = bm * 128 + wm * 64 + i * 16 + mq + r;
        float v = acc[i][j][r] + bv;
        if (MODE == 0) {
          v = fmaxf(v, 0.f);
          out[(size_t)m * N + n] = f2bu(v);
        } else {
          int t = m & 511, b = m >> 9;
          int g = n >> 10, hg = n & 1023;
          out[((size_t)t * 256 + (size_t)(b >> 4) * 64 + (hg >> 4)) * 1024
              + (size_t)g * 256 + (b & 15) * 16 + (hg & 15)] = f2bu(v);
        }
      }
    }
  }
}

// ---------------- persistent LSTM scan ----------------
// 256 WGs = 4 batch-quarters x 64 h-slices(16). Each WG owns W_hh rows
// {g*1024 + hs*16 + r} resident in LDS (128 KB). Per step: gates = h_prev
// [16,1024] @ Wl^T (1 MFMA tile per wave), + gx, nonlin, c in LDS,
// h -> hh[t].
//
// Barrier v3 (this round): the v2 barrier serialized 256 device-scope RMWs
// on ONE cache line (cnt[4]+rel[4] shared a 64B line) -> ~20us/step, the
// dominant cost (MfmaUtil 0.8%). Now: NO atomics-RMW at all.
//   - each WG stores its arrival into its own 64B-strided flag word
//     (parallel, uncontended)
//   - leader WG (hs==0) wave 0 polls all 64 flags with one lane each;
//     when all >= t+1, stores rel[bq] (own 256B line)
//   - other WGs spin on rel[bq]
// Monotone generation values; no reset races. threadfence release before
// flag store / acquire after rel observed preserves cross-XCD semantics.
// XCD-pair mapping: bq=(blk&7)>>1, hs=(blk>>3)*2|(blk&1) puts each bq's
// 64 WGs on one XCD pair (heuristic, perf-only).
__global__ __launch_bounds__(256) void k_scan(const u16* __restrict__ gx,
                                              const u16* __restrict__ Whh,
                                              u16* __restrict__ hh,
                                              u32* __restrict__ bar)
{
  extern __shared__ char smem[];
  u16*  Wl = (u16*)smem;                    // [64][1032]  132096 B
  u16*  hb = (u16*)(smem + 132096);         // [16][520]    16640 B
  float* gl = (float*)(smem + 148736);      // [4][16][16]   4096 B
  float* cl = (float*)(smem + 152832);      // [16][16]      1024 B
  const int tid = threadIdx.x, lane = tid & 63, wv = tid >> 6;
  const int bq = (blockIdx.x & 7) >> 1;
  const int hs = ((blockIdx.x >> 3) << 1) | (blockIdx.x & 1);
  u32* rel   = bar;         // rel[bq] at bar[bq*64]   (256B apart)
  u32* flags = bar + 256;   // flag(bq,hs) at bar[256 + (bq*64+hs)*16]

  // 64 rows x 128 16B-segs (1024 bf16/row).
  for (int idx = tid; idx < 64 * 128; idx += 256) {
    int r = idx >> 7, s = idx & 127;
    int gr = (r >> 4) * 1024 + hs * 16 + (r & 15);
    *(uint4*)&Wl[r * 1032 + s * 8] = *(const uint4*)(Whh + (size_t)gr * 1024 + s * 8);
  }
  cl[tid] = 0.f;
  __syncthreads();

  const int kf = (lane >> 4) * 8;
  const int ra = lane & 15;
  const int rb = wv * 16 + (lane & 15);
  const int srow = tid >> 4;
  const int sseg = tid & 15;

  for (int t = 0; t < 512; t++) {
    // prefetch gx for this step (independent of h(t-1); hide HBM latency
    // under the MFMA phase). Layout: 4 x 512B contiguous per WG.
    const size_t gxo = ((size_t)t * 256 + (size_t)bq * 64 + hs) * 1024 + tid;
    u16 gxr0 = gx[gxo];
    u16 gxr1 = gx[gxo + 256];
    u16 gxr2 = gx[gxo + 512];
    u16 gxr3 = gx[gxo + 768];

    f4 acc = {0.f, 0.f, 0.f, 0.f};
    if (t > 0) {
      const u16* hp = hh + ((size_t)(t - 1) * 64 + bq * 16) * 1024;
      for (int kc = 0; kc < 1024; kc += 512) {
        __syncthreads();
#pragma unroll
        for (int u = 0; u < 4; u++) {
          int s = sseg + u * 16;
          *(uint4*)&hb[srow * 520 + s * 8] = *(const uint4*)(hp + (size_t)srow * 1024 + kc + s * 8);
        }
        __syncthreads();
#pragma unroll
        for (int k = 0; k < 512; k += 32) {
          bf8 a = *(const bf8*)&hb[ra * 520 + k + kf];
          bf8 b = *(const bf8*)&Wl[rb * 1032 + kc + k + kf];
          acc = __builtin_amdgcn_mfma_f32_16x16x32_bf16(a, b, acc, 0, 0, 0);
        }
      }
    }
    {
      int n = lane & 15, m0 = (lane >> 4) * 4;
#pragma unroll
      for (int r = 0; r < 4; r++) gl[wv * 256 + (m0 + r) * 16 + n] = acc[r];
    }
    __syncthreads();
    {
      int b = tid >> 4, hl2 = tid & 15;
      int bg = bq * 16 + b, hg = hs * 16 + hl2;
      float gi = gl[0 * 256 + tid] + b2f(gxr0);
      float gf = gl[1 * 256 + tid] + b2f(gxr1);
      float gg = gl[2 * 256 + tid] + b2f(gxr2);
      float go = gl[3 * 256 + tid] + b2f(gxr3);
      float i_ = 1.f / (1.f + __expf(-gi));
      float f_ = 1.f / (1.f + __expf(-gf));
      float g_ = 1.f - 2.f / (__expf(2.f * gg) + 1.f);   // tanh
      float o_ = 1.f / (1.f + __expf(-go));
      float c = f_ * cl[tid] + i_ * g_;
      cl[tid] = c;
      float h = o_ * (1.f - 2.f / (__expf(2.f * c) + 1.f));
      hh[((size_t)t * 64 + bg) * 1024 + hg] = f2bu(h);
    }
    // ---- per-bq barrier v3 (flag array + leader poll; no RMW) ----
    __syncthreads();               // all h-writes of this WG issued
    if (hs == 0) {
      if (wv == 0) {
        __threadfence();           // release: h visible at coherence point
        if (lane == 0)
          __hip_atomic_store(&flags[(bq * 64) * 16], (u32)(t + 1),
                             __ATOMIC_RELAXED, __HIP_MEMORY_SCOPE_AGENT);
        const u32* fp = &flags[(bq * 64 + lane) * 16];
        while (__hip_atomic_load(fp, __ATOMIC_RELAXED,
                                 __HIP_MEMORY_SCOPE_AGENT) < (u32)(t + 1))
          __builtin_amdgcn_s_sleep(1);
        __threadfence();           // order polls; also acquire for leader
        if (lane == 0)
          __hip_atomic_store(&rel[bq * 64], (u32)(t + 1),
                             __ATOMIC_RELAXED, __HIP_MEMORY_SCOPE_AGENT);
      }
    } else {
      if (tid == 0) {
        __threadfence();           // release
        __hip_atomic_store(&flags[(bq * 64 + hs) * 16], (u32)(t + 1),
                           __ATOMIC_RELAXED, __HIP_MEMORY_SCOPE_AGENT);
        while (__hip_atomic_load(&rel[bq * 64], __ATOMIC_RELAXED,
                                 __HIP_MEMORY_SCOPE_AGENT) < (u32)(t + 1))
          __builtin_amdgcn_s_sleep(2);
        __threadfence();           // acquire: invalidate stale h lines
      }
    }
    __syncthreads();
  }
}

// ---------------- classifier over all (t,b) ----------------
__global__ __launch_bounds__(256) void k_scores(const u16* __restrict__ hh,
                                                const u16* __restrict__ Wcb,
                                                const float* __restrict__ bcls,
                                                float* __restrict__ out)
{
  __shared__ u16 Wc[22 * 1032];   // padded rows
  __shared__ u16 hl[8 * 1032];
  const int tid = threadIdx.x;
  for (int idx = tid; idx < 22 * 128; idx += 256) {
    int r = idx >> 7, s = idx & 127;
    *(uint4*)&Wc[r * 1032 + s * 8] = *(const uint4*)(Wcb + (size_t)r * 1024 + s * 8);
  }
  size_t row0 = (size_t)blockIdx.x * 8;
  for (int idx = tid; idx < 8 * 128; idx += 256) {
    int r = idx >> 7, s = idx & 127;
    *(uint4*)&hl[r * 1032 + s * 8] = *(const uint4*)(hh + (row0 + r) * 1024 + s * 8);
  }
  __syncthreads();
  if (tid < 176) {
    int rl = tid / 22, cls = tid % 22;
    const u16* hp = &hl[rl * 1032];
    const u16* wp = &Wc[cls * 1032];
    float acc = 0.f;
#pragma unroll 4
    for (int k = 0; k < 1024; k += 2) {
      u32 hu = *(const u32*)(hp + k);
      u32 wu = *(const u32*)(wp + k);
      float h0 = __uint_as_float(hu << 16), h1 = __uint_as_float(hu & 0xffff0000u);
      float w0 = __uint_as_float(wu << 16), w1 = __uint_as_float(wu & 0xffff0000u);
      acc += h0 * w0 + h1 * w1;
    }
    size_t r = row0 + rl;
    int t = (int)(r >> 6), b = (int)(r & 63);
    out[((size_t)b * 512 + t) * 22 + cls] = acc + bcls[cls];
  }
}

// ---------------- host ----------------
extern "C" void kernel_launch(void* const* d_in, const int* in_sizes, int n_in,
                              void* d_out, int out_size, void* d_ws, size_t ws_size,
                              hipStream_t stream)
{
  (void)in_sizes; (void)n_in; (void)out_size;
  const float* feat = (const float*)d_in[0];
  const float* Wpre = (const float*)d_in[1];
  const float* bpre = (const float*)d_in[2];
  const float* Wih  = (const float*)d_in[3];
  const float* bih  = (const float*)d_in[4];
  const float* Whh  = (const float*)d_in[5];
  const float* bhh  = (const float*)d_in[6];
  const float* Wcls = (const float*)d_in[7];
  const float* bcls = (const float*)d_in[8];
  char* ws = (char*)d_ws;

  // workspace layout:
  //   featb (201 MB) overlays gx region (dead before gemm<1> writes gx)
  //   hh (64 MB) overlays xb (x dead after gemm<1>)
  const size_t OFF_GX   = 0;          // gx bf16 [512][256][1024] = 256 MB
  const size_t OFF_XB   = 268435456;  // x bf16 [32768][1024] = 64 MB; hh overlay
  const size_t OFF_WPRE = 335544320;  // 6 MB
  const size_t OFF_WIH  = 341835776;  // 8 MB
  const size_t OFF_WHH  = 350224384;  // 8 MB
  const size_t OFF_WCLS = 358612992;  // 44 KB
  const size_t OFF_BSUM = 358658048;  // 16 KB
  const size_t OFF_BAR  = 358674432;  // 32 KB barrier state (rel + flags)
  const size_t NEED     = 358707200;
  if (ws_size < NEED) return;  // graceful fail (absmax) instead of OOB fault

  u16* featb = (u16*)(ws + OFF_GX);
  u16* gxb   = (u16*)(ws + OFF_GX);
  u16* xb    = (u16*)(ws + OFF_XB);
  u16* hhb   = (u16*)(ws + OFF_XB);   // overlay, x dead by scan time
  u16* wpreb = (u16*)(ws + OFF_WPRE);
  u16* wihb  = (u16*)(ws + OFF_WIH);
  u16* whhb  = (u16*)(ws + OFF_WHH);
  u16* wclsb = (u16*)(ws + OFF_WCLS);
  float* bsum = (float*)(ws + OFF_BSUM);
  u32* barp  = (u32*)(ws + OFF_BAR);

  // feature_in: 64*512*3072 = 100,663,296 elems
  k_f2b<<<dim3(49152), dim3(256), 0, stream>>>(feat, featb, 100663296L);
  k_f2b<<<dim3(1536),  dim3(256), 0, stream>>>(Wpre, wpreb, 3145728L);
  k_f2b<<<dim3(2048),  dim3(256), 0, stream>>>(Wih,  wihb,  4194304L);
  k_f2b<<<dim3(2048),  dim3(256), 0, stream>>>(Whh,  whhb,  4194304L);
  k_f2b<<<dim3(11),    dim3(256), 0, stream>>>(Wcls, wclsb, 22528L);
  k_bsum<<<dim3(16),   dim3(256), 0, stream>>>(bih, bhh, bsum, 4096);
  k_zerobar<<<dim3(1), dim3(256), 0, stream>>>(barp);

  k_gemm<0><<<dim3(8, 256),  dim3(256), 0, stream>>>(featb, wpreb, bpre, xb,  32768, 1024, 3072);
  k_gemm<1><<<dim3(32, 256), dim3(256), 0, stream>>>(xb,    wihb,  bsum, gxb, 32768, 4096, 1024);

  const u16* gx_c = gxb;
  const u16* whh_c = whhb;
  u16* hh_p = hhb;
  u32* bar_p = barp;
  void* args[4] = { (void*)&gx_c, (void*)&whh_c, (void*)&hh_p, (void*)&bar_p };
  hipFuncSetAttribute((const void*)k_scan, hipFuncAttributeMaxDynamicSharedMemorySize, 153856);
  hipLaunchCooperativeKernel((void*)k_scan, dim3(256), dim3(256), args, 153856, stream);

  k_scores<<<dim3(4096), dim3(256), 0, stream>>>(hhb, wclsb, bcls, (float*)d_out);
}